// Round 1
// baseline (132.604 us; speedup 1.0000x reference)
//
#include <hip/hip_runtime.h>
#include <math.h>

#define NN 256
#define LL 4096
#define DL 64
#define DC 128
#define KS 15
#define LOUT (LL - KS + 1)   // 4082
#define CST 133              // padded ctb row stride (bank-conflict-free both ways)
#define RSQRT_DC 0.08838834764831843f  // 1/sqrt(128)

// contrib[v*15+k][c] = sum_i emb[v,i] * conv_w[c,i,k]
__global__ void contrib_kernel(const float* __restrict__ emb,
                               const float* __restrict__ conv_w,
                               float* __restrict__ ctb) {
    const int vk = blockIdx.x;          // 0..59 = v*15+k
    const int v = vk / KS, k = vk % KS;
    const int c = threadIdx.x;          // 0..127
    __shared__ float es[DL];
    if (c < DL) es[c] = emb[v * DL + c];
    __syncthreads();
    const float* w = conv_w + (size_t)c * (DL * KS) + k;
    float s = 0.f;
#pragma unroll
    for (int i = 0; i < DL; ++i) s += es[i] * w[i * KS];
    ctb[vk * DC + c] = s;
}

__device__ __forceinline__ float block_sum(float v, float* red, int tid) {
    red[tid] = v; __syncthreads();
#pragma unroll
    for (int s = 128; s > 0; s >>= 1) {
        if (tid < s) red[tid] = red[tid] + red[tid + s];
        __syncthreads();
    }
    float r = red[0]; __syncthreads();
    return r;
}

__device__ __forceinline__ float block_max(float v, float* red, int tid) {
    red[tid] = v; __syncthreads();
#pragma unroll
    for (int s = 128; s > 0; s >>= 1) {
        if (tid < s) red[tid] = fmaxf(red[tid], red[tid + s]);
        __syncthreads();
    }
    float r = red[0]; __syncthreads();
    return r;
}

__global__ __launch_bounds__(256) void encoder_kernel(
    const int* __restrict__ tokens, const float* __restrict__ ctb_g,
    const float* __restrict__ conv_b,
    const float* __restrict__ Wq, const float* __restrict__ bq,
    const float* __restrict__ Wk, const float* __restrict__ bk,
    const float* __restrict__ Wv, const float* __restrict__ bv,
    float* __restrict__ out) {
    const int n = blockIdx.x;
    const int tid = threadIdx.x;

    __shared__ unsigned tok_pack[LL / 4];     // 4 KB, 4 tokens/dword
    __shared__ float escore[LOUT];            // 16 KB: scores, then exp(scores - max)
    __shared__ float ctb[60 * CST];           // 31.9 KB
    __shared__ float rm[DC], qv[DC], qk[DC], zv[DC];
    __shared__ float cf[60];                  // window counts as float
    __shared__ float stab[60];                // scaled score table s[v*15+k]
    __shared__ float Acc[60];                 // attn-weighted histogram A[v*15+k]
    __shared__ float red[256];
    __shared__ int tot[4];
    __shared__ int cnt[KS][4];

#define TOK(p) ((tok_pack[(p) >> 2] >> (((p) & 3) * 8)) & 3u)

    if (tid < 4) tot[tid] = 0;
    if (tid < 60) Acc[tid] = 0.f;
    __syncthreads();

    // ---- stage contrib table into LDS (padded rows) ----
    for (int idx = tid; idx < 60 * DC; idx += 256)
        ctb[(idx >> 7) * CST + (idx & 127)] = ctb_g[idx];

    // ---- pack tokens into LDS + full-range value counts ----
    {
        const int4* tv = (const int4*)(tokens + (size_t)n * LL);
        int c0 = 0, c1 = 0, c2 = 0, c3 = 0;
        for (int p4 = tid; p4 < LL / 4; p4 += 256) {
            int4 t4 = tv[p4];
            tok_pack[p4] = (unsigned)t4.x | ((unsigned)t4.y << 8) |
                           ((unsigned)t4.z << 16) | ((unsigned)t4.w << 24);
            c0 += (t4.x == 0) + (t4.y == 0) + (t4.z == 0) + (t4.w == 0);
            c1 += (t4.x == 1) + (t4.y == 1) + (t4.z == 1) + (t4.w == 1);
            c2 += (t4.x == 2) + (t4.y == 2) + (t4.z == 2) + (t4.w == 2);
            c3 += (t4.x == 3) + (t4.y == 3) + (t4.z == 3) + (t4.w == 3);
        }
        atomicAdd(&tot[0], c0); atomicAdd(&tot[1], c1);
        atomicAdd(&tot[2], c2); atomicAdd(&tot[3], c3);
    }
    __syncthreads();

    // ---- per-k window counts: cnt[k][v] = #{p in [k, k+LOUT) : tok=v} ----
    if (tid < KS) {
        const int k = tid;
        int h0 = 0, h1 = 0, h2 = 0, h3 = 0;
        for (int p = 0; p < k; ++p) {
            int v = (int)TOK(p);
            h0 += (v == 0); h1 += (v == 1); h2 += (v == 2); h3 += (v == 3);
        }
        for (int p = k + LOUT; p < LL; ++p) {
            int v = (int)TOK(p);
            h0 += (v == 0); h1 += (v == 1); h2 += (v == 2); h3 += (v == 3);
        }
        cnt[k][0] = tot[0] - h0; cnt[k][1] = tot[1] - h1;
        cnt[k][2] = tot[2] - h2; cnt[k][3] = tot[3] - h3;
    }
    __syncthreads();
    if (tid < 60) cf[tid] = (float)cnt[tid % KS][tid / KS];
    __syncthreads();

    // ---- read_mean ----
    if (tid < DC) {
        float s = 0.f;
#pragma unroll
        for (int j = 0; j < 60; ++j) s += cf[j] * ctb[j * CST + tid];
        rm[tid] = conv_b[tid] + s * (1.0f / (float)LOUT);
    }
    __syncthreads();

    // ---- q = rm @ Wq.T + bq ----
    if (tid < DC) {
        const float4* wr = (const float4*)(Wq + (size_t)tid * DC);
        const float4* r4 = (const float4*)rm;
        float s = 0.f;
#pragma unroll
        for (int j = 0; j < DC / 4; ++j) {
            float4 w = wr[j], r = r4[j];
            s += w.x * r.x + w.y * r.y + w.z * r.z + w.w * r.w;
        }
        qv[tid] = s + bq[tid];
    }
    __syncthreads();

    // ---- qk[d] = sum_c q[c] * Wk[c,d] ----
    if (tid < DC) {
        float s = 0.f;
        for (int c = 0; c < DC; ++c) s += qv[c] * Wk[(size_t)c * DC + tid];
        qk[tid] = s;
    }
    __syncthreads();

    // ---- scalar score table + base ----
    if (tid < 60) {
        float s = 0.f;
#pragma unroll
        for (int c = 0; c < DC; ++c) s += ctb[tid * CST + c] * qk[c];
        stab[tid] = s * RSQRT_DC;
    }
    float term = 0.f;
    if (tid < DC) term = conv_b[tid] * qk[tid] + qv[tid] * bk[tid];
    const float base = block_sum(term, red, tid) * RSQRT_DC;

    // ---- scores + online softmax ----
    float lmax = -3.4e38f;
    for (int t = tid; t < LOUT; t += 256) {
        float s = base;
#pragma unroll
        for (int k = 0; k < KS; ++k) s += stab[(int)TOK(t + k) * KS + k];
        escore[t] = s;
        lmax = fmaxf(lmax, s);
    }
    const float m = block_max(lmax, red, tid);
    float lsum = 0.f;
    for (int t = tid; t < LOUT; t += 256) {
        float e = __expf(escore[t] - m);
        escore[t] = e;
        lsum += e;
    }
    const float S = block_sum(lsum, red, tid);
    const float invS = 1.0f / S;

    // ---- attn-weighted token histogram A[k][v] ----
    float a[KS][4];
#pragma unroll
    for (int k = 0; k < KS; ++k)
#pragma unroll
        for (int u = 0; u < 4; ++u) a[k][u] = 0.f;
    for (int t = tid; t < LOUT; t += 256) {
        float e = escore[t];
#pragma unroll
        for (int k = 0; k < KS; ++k) {
            int v = (int)TOK(t + k);
            a[k][0] += (v == 0) ? e : 0.f;
            a[k][1] += (v == 1) ? e : 0.f;
            a[k][2] += (v == 2) ? e : 0.f;
            a[k][3] += (v == 3) ? e : 0.f;
        }
    }
    {
        const int lane = tid & 63;
#pragma unroll
        for (int k = 0; k < KS; ++k) {
#pragma unroll
            for (int u = 0; u < 4; ++u) {
                float val = a[k][u];
#pragma unroll
                for (int off = 32; off > 0; off >>= 1)
                    val += __shfl_down(val, off, 64);
                if (lane == 0) atomicAdd(&Acc[u * KS + k], val);
            }
        }
    }
    __syncthreads();

    // ---- z = conv_b + (1/S) * sum_j Acc[j] * contrib[j] ----
    if (tid < DC) {
        float s = 0.f;
#pragma unroll
        for (int j = 0; j < 60; ++j) s += Acc[j] * ctb[j * CST + tid];
        zv[tid] = conv_b[tid] + s * invS;
    }
    __syncthreads();

    // ---- out = z @ Wv.T + bv ----
    if (tid < DC) {
        const float4* wr = (const float4*)(Wv + (size_t)tid * DC);
        const float4* z4 = (const float4*)zv;
        float s = 0.f;
#pragma unroll
        for (int j = 0; j < DC / 4; ++j) {
            float4 w = wr[j], z = z4[j];
            s += w.x * z.x + w.y * z.y + w.z * z.z + w.w * z.w;
        }
        out[(size_t)n * DC + tid] = s + bv[tid];
    }
#undef TOK
}

extern "C" void kernel_launch(void* const* d_in, const int* in_sizes, int n_in,
                              void* d_out, int out_size, void* d_ws, size_t ws_size,
                              hipStream_t stream) {
    const int*   tokens = (const int*)d_in[0];
    const float* emb    = (const float*)d_in[1];
    const float* conv_w = (const float*)d_in[2];
    const float* conv_b = (const float*)d_in[3];
    const float* Wq     = (const float*)d_in[4];
    const float* bq     = (const float*)d_in[5];
    const float* Wk     = (const float*)d_in[6];
    const float* bk     = (const float*)d_in[7];
    const float* Wv     = (const float*)d_in[8];
    const float* bv     = (const float*)d_in[9];
    float* out = (float*)d_out;
    float* ctb = (float*)d_ws;   // 60*128 floats = 30720 B

    contrib_kernel<<<60, 128, 0, stream>>>(emb, conv_w, ctb);
    encoder_kernel<<<NN, 256, 0, stream>>>(tokens, ctb, conv_b,
                                           Wq, bq, Wk, bk, Wv, bv, out);
}

// Round 2
// 103.439 us; speedup vs baseline: 1.2820x; 1.2820x over previous
//
#include <hip/hip_runtime.h>
#include <math.h>

#define NN 256
#define LL 4096
#define DL 64
#define DC 128
#define KS 15
#define LOUT (LL - KS + 1)   // 4082
#define CST 133              // padded ctb row stride
#define RSQRT_DC 0.08838834764831843f  // 1/sqrt(128)

// ctb[(v*15+k)*128 + c] = sum_i emb[v,i] * conv_w[c,i,k]
// one block per c: stage conv_w[c] (contiguous 960 floats) coalesced.
__global__ __launch_bounds__(128) void contrib_kernel(const float* __restrict__ emb,
                                                      const float* __restrict__ conv_w,
                                                      float* __restrict__ ctb) {
    const int c = blockIdx.x;            // 0..127
    const int tid = threadIdx.x;
    __shared__ float ws[DL][16];         // [i][k], k padded to 16
    __shared__ float es[4][DL];
    const float* wsrc = conv_w + (size_t)c * (DL * KS);
    for (int idx = tid; idx < DL * KS; idx += 128) ws[idx / KS][idx % KS] = wsrc[idx];
    for (int idx = tid; idx < 4 * DL; idx += 128) es[idx >> 6][idx & 63] = emb[idx];
    __syncthreads();
    if (tid < 60) {
        const int v = tid / KS, k = tid % KS;
        float s = 0.f;
#pragma unroll
        for (int i = 0; i < DL; ++i) s += es[v][i] * ws[i][k];
        ctb[tid * DC + c] = s;
    }
}

__device__ __forceinline__ float block_sum(float v, float* red8, int tid) {
#pragma unroll
    for (int off = 32; off > 0; off >>= 1) v += __shfl_down(v, off, 64);
    if ((tid & 63) == 0) red8[tid >> 6] = v;
    __syncthreads();
    float r = ((red8[0] + red8[1]) + (red8[2] + red8[3])) +
              ((red8[4] + red8[5]) + (red8[6] + red8[7]));
    __syncthreads();
    return r;
}

__device__ __forceinline__ float block_max(float v, float* red8, int tid) {
#pragma unroll
    for (int off = 32; off > 0; off >>= 1) v = fmaxf(v, __shfl_down(v, off, 64));
    if ((tid & 63) == 0) red8[tid >> 6] = v;
    __syncthreads();
    float r = fmaxf(fmaxf(fmaxf(red8[0], red8[1]), fmaxf(red8[2], red8[3])),
                    fmaxf(fmaxf(red8[4], red8[5]), fmaxf(red8[6], red8[7])));
    __syncthreads();
    return r;
}

__global__ __launch_bounds__(512) void encoder_kernel(
    const int* __restrict__ tokens, const float* __restrict__ ctb_g,
    const float* __restrict__ conv_b,
    const float* __restrict__ Wq, const float* __restrict__ bq,
    const float* __restrict__ Wk, const float* __restrict__ bk,
    const float* __restrict__ Wv, const float* __restrict__ bv,
    float* __restrict__ out) {
    const int n = blockIdx.x;
    const int tid = threadIdx.x;

    __shared__ __align__(16) float esc[16 + LL];  // e-values, 16-slot zero guard below, zeros above LOUT
    __shared__ unsigned tok2[258];                // 2-bit packed tokens, 16/dword, +2 zero pad
    __shared__ float ctb[60 * CST];               // contrib table, padded rows
    __shared__ float Tt[4 * 256];                 // score chunk tables
    __shared__ float rm[DC], qv[DC], qk[DC], zv[DC];
    __shared__ float stab[60], cf[60], Acc[60];
    __shared__ float red8[8];
    __shared__ int totw[4][4];                    // per-wave token-value counts
    __shared__ int cnt[KS][4];

#define TOK2(p) ((tok2[(p) >> 4] >> (2 * ((p) & 15))) & 3u)

    // ---- init ----
    for (int i = tid; i < 16 + LL; i += 512) esc[i] = 0.f;
    if (tid < 60) Acc[tid] = 0.f;
    if (tid < 2) tok2[256 + tid] = 0u;
    for (int idx = tid; idx < 60 * DC; idx += 512)
        ctb[(idx >> 7) * CST + (idx & 127)] = ctb_g[idx];

    // ---- pack tokens to 2 bits + per-wave value counts ----
    if (tid < 256) {
        const int4* tv = (const int4*)(tokens + (size_t)n * LL) + tid * 4;
        unsigned w = 0;
#pragma unroll
        for (int m = 0; m < 4; ++m) {
            int4 t4 = tv[m];
            w |= ((unsigned)t4.x | ((unsigned)t4.y << 2) |
                  ((unsigned)t4.z << 4) | ((unsigned)t4.w << 6)) << (8 * m);
        }
        tok2[tid] = w;
        int c0, c1, c2, c3;
        {
            unsigned y, z;
            y = w;                      z = (y | (y >> 1)) & 0x55555555u; c0 = 16 - __popc(z);
            y = w ^ 0x55555555u;        z = (y | (y >> 1)) & 0x55555555u; c1 = 16 - __popc(z);
            y = w ^ 0xAAAAAAAAu;        z = (y | (y >> 1)) & 0x55555555u; c2 = 16 - __popc(z);
            y = w ^ 0xFFFFFFFFu;        z = (y | (y >> 1)) & 0x55555555u; c3 = 16 - __popc(z);
        }
#pragma unroll
        for (int off = 32; off > 0; off >>= 1) {
            c0 += __shfl_down(c0, off, 64); c1 += __shfl_down(c1, off, 64);
            c2 += __shfl_down(c2, off, 64); c3 += __shfl_down(c3, off, 64);
        }
        if ((tid & 63) == 0) {
            const int wv = tid >> 6;
            totw[wv][0] = c0; totw[wv][1] = c1; totw[wv][2] = c2; totw[wv][3] = c3;
        }
    }
    __syncthreads();

    // ---- per-k window counts via edge correction ----
    if (tid < KS) {
        const int k = tid;
        int h0 = 0, h1 = 0, h2 = 0, h3 = 0;
        for (int p = 0; p < k; ++p) {
            int v = (int)TOK2(p);
            h0 += (v == 0); h1 += (v == 1); h2 += (v == 2); h3 += (v == 3);
        }
        for (int p = k + LOUT; p < LL; ++p) {
            int v = (int)TOK2(p);
            h0 += (v == 0); h1 += (v == 1); h2 += (v == 2); h3 += (v == 3);
        }
        cnt[k][0] = (totw[0][0] + totw[1][0] + totw[2][0] + totw[3][0]) - h0;
        cnt[k][1] = (totw[0][1] + totw[1][1] + totw[2][1] + totw[3][1]) - h1;
        cnt[k][2] = (totw[0][2] + totw[1][2] + totw[2][2] + totw[3][2]) - h2;
        cnt[k][3] = (totw[0][3] + totw[1][3] + totw[2][3] + totw[3][3]) - h3;
    }
    __syncthreads();
    if (tid < 60) cf[tid] = (float)cnt[tid % KS][tid / KS];
    __syncthreads();

    // ---- read_mean ----
    if (tid < DC) {
        float s = 0.f;
#pragma unroll
        for (int j = 0; j < 60; ++j) s += cf[j] * ctb[j * CST + tid];
        rm[tid] = conv_b[tid] + s * (1.0f / (float)LOUT);
    }
    __syncthreads();

    // ---- q = rm @ Wq.T + bq ----
    if (tid < DC) {
        const float4* wr = (const float4*)(Wq + (size_t)tid * DC);
        const float4* r4 = (const float4*)rm;
        float s = 0.f;
#pragma unroll
        for (int j = 0; j < DC / 4; ++j) {
            float4 w = wr[j], r = r4[j];
            s += w.x * r.x + w.y * r.y + w.z * r.z + w.w * r.w;
        }
        qv[tid] = s + bq[tid];
    }
    __syncthreads();

    // ---- qk[d] = sum_c q[c] * Wk[c,d] (coalesced columns) ----
    if (tid < DC) {
        float s = 0.f;
        for (int c = 0; c < DC; ++c) s += qv[c] * Wk[(size_t)c * DC + tid];
        qk[tid] = s;
    }
    __syncthreads();

    // ---- scalar score table + base ----
    if (tid < 60) {
        float s = 0.f;
#pragma unroll
        for (int c = 0; c < DC; ++c) s += ctb[tid * CST + c] * qk[c];
        stab[tid] = s * RSQRT_DC;
    }
    float term = 0.f;
    if (tid < DC) term = conv_b[tid] * qk[tid] + qv[tid] * bk[tid];
    const float base = block_sum(term, red8, tid) * RSQRT_DC;  // also syncs stab

    // ---- build 4 chunk tables: Tt[j*256+b] = sum_m stab[tok_m(b)*15 + 4j+m] ----
    for (int e = tid; e < 1024; e += 512) {
        const int j = e >> 8, b = e & 255;
        float s = stab[(b & 3) * KS + 4 * j] +
                  stab[((b >> 2) & 3) * KS + 4 * j + 1] +
                  stab[((b >> 4) & 3) * KS + 4 * j + 2];
        if (j < 3) s += stab[((b >> 6) & 3) * KS + 4 * j + 3];
        Tt[e] = s;
    }
    __syncthreads();

    // ---- scores: each thread 8 consecutive positions from a 64-bit register window ----
    const unsigned d0 = tok2[tid >> 1];
    const unsigned d1 = tok2[(tid >> 1) + 1];
    const unsigned long long W = (unsigned long long)d0 | ((unsigned long long)d1 << 32);
    const int sbase = (tid & 1) << 4;
    const int t0 = tid * 8;
    float lmax = -3.4e38f;
    {
        float sreg[8];
#pragma unroll
        for (int p = 0; p < 8; ++p) {
            const unsigned w = (unsigned)(W >> (sbase + 2 * p));
            sreg[p] = base + Tt[w & 255] + Tt[256 + ((w >> 8) & 255)] +
                      Tt[512 + ((w >> 16) & 255)] + Tt[768 + ((w >> 24) & 63)];
        }
#pragma unroll
        for (int p = 0; p < 8; ++p) {
            if (t0 + p < LOUT) { esc[16 + t0 + p] = sreg[p]; lmax = fmaxf(lmax, sreg[p]); }
        }
    }
    const float m = block_max(lmax, red8, tid);

    // ---- exp + sum ----
    float lsum = 0.f;
    for (int t = tid; t < LOUT; t += 512) {
        float e = __expf(esc[16 + t] - m);
        esc[16 + t] = e;
        lsum += e;
    }
    const float S = block_sum(lsum, red8, tid);
    const float invS = 1.0f / S;

    // ---- attn-weighted histogram, inverted: A[k,v] = sum_p 1[tok_p=v] * e[p-k] ----
    // e-window in registers via float4 LDS reads; v=0 recovered as S - A1 - A2 - A3.
    {
        float ew[24];
        const float4* ep = (const float4*)(esc + t0);   // esc[t0 .. t0+23] = e[t0-16 .. t0+7]
#pragma unroll
        for (int i = 0; i < 6; ++i) {
            float4 f = ep[i];
            ew[4 * i] = f.x; ew[4 * i + 1] = f.y; ew[4 * i + 2] = f.z; ew[4 * i + 3] = f.w;
        }
        float a1[KS], a2[KS], a3[KS];
#pragma unroll
        for (int k = 0; k < KS; ++k) { a1[k] = 0.f; a2[k] = 0.f; a3[k] = 0.f; }
#pragma unroll
        for (int p = 0; p < 8; ++p) {
            const int v = (int)((W >> (sbase + 2 * p)) & 3ull);
            const float m1 = (v == 1) ? 1.f : 0.f;
            const float m2 = (v == 2) ? 1.f : 0.f;
            const float m3 = (v == 3) ? 1.f : 0.f;
#pragma unroll
            for (int k = 0; k < KS; ++k) {
                const float e = ew[16 + p - k];
                a1[k] += m1 * e; a2[k] += m2 * e; a3[k] += m3 * e;
            }
        }
        const int lane = tid & 63;
#pragma unroll
        for (int k = 0; k < KS; ++k) {
            float v1 = a1[k], v2 = a2[k], v3 = a3[k];
#pragma unroll
            for (int off = 32; off > 0; off >>= 1) {
                v1 += __shfl_down(v1, off, 64);
                v2 += __shfl_down(v2, off, 64);
                v3 += __shfl_down(v3, off, 64);
            }
            if (lane == 0) {
                atomicAdd(&Acc[KS + k], v1);
                atomicAdd(&Acc[2 * KS + k], v2);
                atomicAdd(&Acc[3 * KS + k], v3);
            }
        }
    }
    __syncthreads();
    if (tid < KS) Acc[tid] = S - Acc[KS + tid] - Acc[2 * KS + tid] - Acc[3 * KS + tid];
    __syncthreads();

    // ---- z = conv_b + (1/S) * sum_j Acc[j] * ctb[j] ----
    if (tid < DC) {
        float s = 0.f;
#pragma unroll
        for (int j = 0; j < 60; ++j) s += Acc[j] * ctb[j * CST + tid];
        zv[tid] = conv_b[tid] + s * invS;
    }
    __syncthreads();

    // ---- out = z @ Wv.T + bv ----
    if (tid < DC) {
        const float4* wr = (const float4*)(Wv + (size_t)tid * DC);
        const float4* z4 = (const float4*)zv;
        float s = 0.f;
#pragma unroll
        for (int j = 0; j < DC / 4; ++j) {
            float4 w = wr[j], z = z4[j];
            s += w.x * z.x + w.y * z.y + w.z * z.z + w.w * z.w;
        }
        out[(size_t)n * DC + tid] = s + bv[tid];
    }
#undef TOK2
}

extern "C" void kernel_launch(void* const* d_in, const int* in_sizes, int n_in,
                              void* d_out, int out_size, void* d_ws, size_t ws_size,
                              hipStream_t stream) {
    const int*   tokens = (const int*)d_in[0];
    const float* emb    = (const float*)d_in[1];
    const float* conv_w = (const float*)d_in[2];
    const float* conv_b = (const float*)d_in[3];
    const float* Wq     = (const float*)d_in[4];
    const float* bq     = (const float*)d_in[5];
    const float* Wk     = (const float*)d_in[6];
    const float* bk     = (const float*)d_in[7];
    const float* Wv     = (const float*)d_in[8];
    const float* bv     = (const float*)d_in[9];
    float* out = (float*)d_out;
    float* ctb = (float*)d_ws;   // 60*128 floats = 30720 B

    contrib_kernel<<<DC, 128, 0, stream>>>(emb, conv_w, ctb);
    encoder_kernel<<<NN, 512, 0, stream>>>(tokens, ctb, conv_b,
                                           Wq, bq, Wk, bk, Wv, bv, out);
}